// Round 6
// baseline (66279.987 us; speedup 1.0000x reference)
//
#include <hip/hip_runtime.h>
#include <hip/hip_bf16.h>

#define D_MODEL 256
#define N_LAYER 16
#define VOCAB 24
#define D_INNER 512
#define D_STATE 16
#define D_CONV 4
#define DT_RANK 16
#define BATCH 2
#define SEQ 2048
#define NTOK (BATCH*SEQ)   /* 4096 */
#define EPS 1e-5f

__device__ __forceinline__ float silu(float v) { return v / (1.f + expf(-v)); }

// ---------------------------------------------------------------- embedding
__global__ void k_embed(const int* __restrict__ ids, const float* __restrict__ emb,
                        float* __restrict__ residual) {
    int idx = blockIdx.x * 256 + threadIdx.x;      // NTOK*256
    int tok = idx >> 8, c = idx & 255;
    residual[idx] = emb[ids[tok] * D_MODEL + c];
}

// ---------------------------------------------------------------- rmsnorm
__global__ void k_rmsnorm(const float* __restrict__ residual, const float* __restrict__ w,
                          float* __restrict__ hn) {
    __shared__ float red[256];
    int tok = blockIdx.x, c = threadIdx.x;
    float v = residual[tok * 256 + c];
    red[c] = v * v;
    __syncthreads();
    for (int st = 128; st > 0; st >>= 1) {
        if (c < st) red[c] += red[c + st];
        __syncthreads();
    }
    float scale = rsqrtf(red[0] * (1.f / 256.f) + EPS);
    hn[tok * 256 + c] = v * scale * w[c];
}

// ------------------------------------- gemm1: one thread per output element
__global__ void k_gemm1_naive(const float* __restrict__ A, const float* __restrict__ W,
                              float* __restrict__ xh, float* __restrict__ zb) {
    int idx = blockIdx.x * 256 + threadIdx.x;      // NTOK*1024
    int m = idx >> 10, n = idx & 1023;
    const float* a = A + (size_t)m * 256;
    const float* w = W + (size_t)n * 256;
    float acc = 0.f;
    for (int k = 0; k < 256; k++) acc += a[k] * w[k];
    if (n < 512) xh[(size_t)m * 512 + n] = acc;
    else         zb[(size_t)m * 512 + n - 512] = acc;
}

// ------------------------------------------------- depthwise conv + silu
__global__ void k_conv(const float* __restrict__ xh, const float* __restrict__ cw,
                       const float* __restrict__ cb, float* __restrict__ xb) {
    int idx = blockIdx.x * 256 + threadIdx.x;      // NTOK*512
    int tok = idx >> 9, d = idx & 511;
    int b = tok >> 11, l = tok & 2047;
    const float* base = xh + (size_t)(b * 2048) * 512 + d;
    float acc = cb[d];
    for (int k = 0; k < 4; k++) {
        int t = l - 3 + k;
        if (t >= 0) acc += base[(size_t)t * 512] * cw[d * 4 + k];
    }
    xb[idx] = silu(acc);
}

// ---------------------------------------------------------------- x_proj
__global__ void k_xproj(const float* __restrict__ xb, const float* __restrict__ xw,
                        float* __restrict__ dbc) {
    int idx = blockIdx.x * 256 + threadIdx.x;      // NTOK*48
    int tok = idx / 48, e = idx % 48;
    const float* x = xb + (size_t)tok * 512;
    const float* w = xw + (size_t)e * 512;
    float acc = 0.f;
    for (int k = 0; k < 512; k++) acc += x[k] * w[k];
    dbc[(size_t)tok * 48 + e] = acc;
}

// ------------------- selective scan: one thread per (b,d), 16 states in regs
__global__ void k_scan(const float* __restrict__ dbc, const float* __restrict__ xb,
                       const float* __restrict__ zb, const float* __restrict__ dtw,
                       const float* __restrict__ dtb, const float* __restrict__ a_log,
                       const float* __restrict__ Dp, float* __restrict__ yb) {
    int idx = blockIdx.x * 256 + threadIdx.x;      // 1024 threads
    if (idx >= BATCH * D_INNER) return;
    int b = idx >> 9, d = idx & 511;
    float A[16], h[16], wdt[16];
    for (int s = 0; s < 16; s++) {
        A[s] = -expf(a_log[d * 16 + s]);
        h[s] = 0.f;
        wdt[s] = dtw[d * 16 + s];
    }
    float Dv = Dp[d], bdt = dtb[d];
    for (int t = 0; t < SEQ; t++) {
        int tok = b * SEQ + t;
        const float* row = dbc + (size_t)tok * 48;
        float dtr = bdt;
        for (int r = 0; r < 16; r++) dtr += row[r] * wdt[r];
        float dt = (dtr > 20.f) ? dtr : log1pf(expf(dtr));
        float x = xb[(size_t)tok * 512 + d];
        float z = zb[(size_t)tok * 512 + d];
        float acc = 0.f;
        for (int s = 0; s < 16; s++) {
            h[s] = expf(dt * A[s]) * h[s] + dt * row[16 + s] * x;
            acc += h[s] * row[32 + s];
        }
        float y = acc + Dv * x;
        yb[(size_t)tok * 512 + d] = y * silu(z);
    }
}

// ------------------------------------- gemm2: residual += y @ out_w^T
__global__ void k_gemm2_naive(const float* __restrict__ yb, const float* __restrict__ W,
                              float* __restrict__ residual) {
    int idx = blockIdx.x * 256 + threadIdx.x;      // NTOK*256
    int m = idx >> 8, n = idx & 255;
    const float* a = yb + (size_t)m * 512;
    const float* w = W + (size_t)n * 512;
    float acc = 0.f;
    for (int k = 0; k < 512; k++) acc += a[k] * w[k];
    residual[idx] += acc;
}

// ---------------------------------------------------------------- lm head (f32 out)
__global__ void k_head(const float* __restrict__ hn, const float* __restrict__ lw,
                       float* __restrict__ out) {
    int idx = blockIdx.x * 256 + threadIdx.x;      // NTOK*20 = 81920
    int tok = idx / 20, v = idx % 20;
    const float* a = hn + (size_t)tok * 256;
    const float* w = lw + (size_t)v * 256;
    float acc = 0.f;
    for (int k = 0; k < 256; k++) acc += a[k] * w[k];
    out[idx] = acc;
}

extern "C" void kernel_launch(void* const* d_in, const int* in_sizes, int n_in,
                              void* d_out, int out_size, void* d_ws, size_t ws_size,
                              hipStream_t stream) {
    const int*   ids    = (const int*)d_in[0];
    const float* emb    = (const float*)d_in[1];
    const float* in_w   = (const float*)d_in[2];
    const float* conv_w = (const float*)d_in[3];
    const float* conv_b = (const float*)d_in[4];
    const float* x_w    = (const float*)d_in[5];
    const float* dt_w   = (const float*)d_in[6];
    const float* dt_b   = (const float*)d_in[7];
    const float* a_log  = (const float*)d_in[8];
    const float* d_skip = (const float*)d_in[9];
    const float* out_w  = (const float*)d_in[10];
    const float* norm_w = (const float*)d_in[11];
    const float* norm_f = (const float*)d_in[12];
    const float* lm_w   = (const float*)d_in[13];
    float* out = (float*)d_out;   // reference output dtype is float32

    // ---- workspace layout, all f32, no aliasing: 42,729,472 bytes ----
    // (round-5 probe confirmed ws_size >= this)
    char* ws = (char*)d_ws;
    float* residual = (float*)(ws + 0);            // NTOK*256 = 4 MB
    float* hn       = (float*)(ws + 4194304);      // NTOK*256 = 4 MB
    float* xh       = (float*)(ws + 8388608);      // NTOK*512 = 8 MB
    float* zb       = (float*)(ws + 16777216);     // NTOK*512 = 8 MB
    float* xb       = (float*)(ws + 25165824);     // NTOK*512 = 8 MB
    float* dbc      = (float*)(ws + 33554432);     // NTOK*48  = 768 KB
    float* yb       = (float*)(ws + 34340864);     // NTOK*512 = 8 MB

    k_embed<<<(NTOK * 256) / 256, 256, 0, stream>>>(ids, emb, residual);

    for (int i = 0; i < N_LAYER; i++) {
        k_rmsnorm<<<NTOK, 256, 0, stream>>>(residual, norm_w + i * D_MODEL, hn);
        k_gemm1_naive<<<(NTOK * 1024) / 256, 256, 0, stream>>>(
            hn, in_w + (size_t)i * 1024 * 256, xh, zb);
        k_conv<<<(NTOK * 512) / 256, 256, 0, stream>>>(
            xh, conv_w + (size_t)i * 512 * 4, conv_b + (size_t)i * 512, xb);
        k_xproj<<<(NTOK * 48) / 256, 256, 0, stream>>>(
            xb, x_w + (size_t)i * 48 * 512, dbc);
        k_scan<<<4, 256, 0, stream>>>(dbc, xb, zb,
                                      dt_w + (size_t)i * 512 * 16,
                                      dt_b + (size_t)i * 512,
                                      a_log + (size_t)i * 512 * 16,
                                      d_skip + (size_t)i * 512, yb);
        k_gemm2_naive<<<(NTOK * 256) / 256, 256, 0, stream>>>(
            yb, out_w + (size_t)i * 256 * 512, residual);
    }

    k_rmsnorm<<<NTOK, 256, 0, stream>>>(residual, norm_f, hn);
    k_head<<<320, 256, 0, stream>>>(hn, lm_w, out);
}

// Round 7
// 4629.704 us; speedup vs baseline: 14.3162x; 14.3162x over previous
//
#include <hip/hip_runtime.h>
#include <hip/hip_bf16.h>

#define D_MODEL 256
#define N_LAYER 16
#define VOCAB 24
#define D_INNER 512
#define D_STATE 16
#define D_CONV 4
#define DT_RANK 16
#define BATCH 2
#define SEQ 2048
#define NTOK (BATCH*SEQ)   /* 4096 */
#define EPS 1e-5f
#define NC 16              /* scan chunks */
#define CL (SEQ/NC)        /* 128 tokens per chunk */

__device__ __forceinline__ float silu(float v) { return v / (1.f + expf(-v)); }

// ---------------------------------------------------------------- embedding
__global__ void k_embed(const int* __restrict__ ids, const float* __restrict__ emb,
                        float* __restrict__ residual) {
    int idx = blockIdx.x * 256 + threadIdx.x;      // NTOK*256
    int tok = idx >> 8, c = idx & 255;
    residual[idx] = emb[ids[tok] * D_MODEL + c];
}

// ---------------------------------------------------------------- rmsnorm
__global__ void k_rmsnorm(const float* __restrict__ residual, const float* __restrict__ w,
                          float* __restrict__ hn) {
    __shared__ float red[256];
    int tok = blockIdx.x, c = threadIdx.x;
    float v = residual[tok * 256 + c];
    red[c] = v * v;
    __syncthreads();
    for (int st = 128; st > 0; st >>= 1) {
        if (c < st) red[c] += red[c + st];
        __syncthreads();
    }
    float scale = rsqrtf(red[0] * (1.f / 256.f) + EPS);
    hn[tok * 256 + c] = v * scale * w[c];
}

// ---------------------- gemm1 tiled: [NTOK,256] @ [1024,256]^T -> split x/z
__global__ __launch_bounds__(256) void k_gemm1_tiled(const float* __restrict__ A,
                                                     const float* __restrict__ W,
                                                     float* __restrict__ xh,
                                                     float* __restrict__ zb) {
    __shared__ __align__(16) float As[16][64];
    __shared__ __align__(16) float Ws[16][64];
    const int bm = blockIdx.x * 64, bn = blockIdx.y * 64;
    const int tid = threadIdx.x;
    const int tx = tid & 15, ty = tid >> 4;
    const int lm = tid >> 2;         // 0..63
    const int lk = (tid & 3) * 4;    // 0,4,8,12
    float acc[4][4] = {};
    for (int k0 = 0; k0 < 256; k0 += 16) {
        float4 av = *(const float4*)(A + (size_t)(bm + lm) * 256 + k0 + lk);
        float4 wv = *(const float4*)(W + (size_t)(bn + lm) * 256 + k0 + lk);
        __syncthreads();
        As[lk + 0][lm] = av.x; As[lk + 1][lm] = av.y;
        As[lk + 2][lm] = av.z; As[lk + 3][lm] = av.w;
        Ws[lk + 0][lm] = wv.x; Ws[lk + 1][lm] = wv.y;
        Ws[lk + 2][lm] = wv.z; Ws[lk + 3][lm] = wv.w;
        __syncthreads();
        #pragma unroll
        for (int kk = 0; kk < 16; kk++) {
            float4 a = *(const float4*)&As[kk][ty * 4];
            float4 b = *(const float4*)&Ws[kk][tx * 4];
            acc[0][0] += a.x * b.x; acc[0][1] += a.x * b.y; acc[0][2] += a.x * b.z; acc[0][3] += a.x * b.w;
            acc[1][0] += a.y * b.x; acc[1][1] += a.y * b.y; acc[1][2] += a.y * b.z; acc[1][3] += a.y * b.w;
            acc[2][0] += a.z * b.x; acc[2][1] += a.z * b.y; acc[2][2] += a.z * b.z; acc[2][3] += a.z * b.w;
            acc[3][0] += a.w * b.x; acc[3][1] += a.w * b.y; acc[3][2] += a.w * b.z; acc[3][3] += a.w * b.w;
        }
    }
    #pragma unroll
    for (int i = 0; i < 4; i++) {
        size_t row = (size_t)(bm + ty * 4 + i);
        float4 v = make_float4(acc[i][0], acc[i][1], acc[i][2], acc[i][3]);
        if (bn < 512) *(float4*)(xh + row * 512 + bn + tx * 4) = v;          // uniform per block
        else          *(float4*)(zb + row * 512 + (bn - 512) + tx * 4) = v;
    }
}

// ------------------- gemm2 tiled: residual += [NTOK,512] @ [256,512]^T
__global__ __launch_bounds__(256) void k_gemm2_tiled(const float* __restrict__ A,
                                                     const float* __restrict__ W,
                                                     float* __restrict__ residual) {
    __shared__ __align__(16) float As[16][64];
    __shared__ __align__(16) float Ws[16][64];
    const int bm = blockIdx.x * 64, bn = blockIdx.y * 64;
    const int tid = threadIdx.x;
    const int tx = tid & 15, ty = tid >> 4;
    const int lm = tid >> 2;
    const int lk = (tid & 3) * 4;
    float acc[4][4] = {};
    for (int k0 = 0; k0 < 512; k0 += 16) {
        float4 av = *(const float4*)(A + (size_t)(bm + lm) * 512 + k0 + lk);
        float4 wv = *(const float4*)(W + (size_t)(bn + lm) * 512 + k0 + lk);
        __syncthreads();
        As[lk + 0][lm] = av.x; As[lk + 1][lm] = av.y;
        As[lk + 2][lm] = av.z; As[lk + 3][lm] = av.w;
        Ws[lk + 0][lm] = wv.x; Ws[lk + 1][lm] = wv.y;
        Ws[lk + 2][lm] = wv.z; Ws[lk + 3][lm] = wv.w;
        __syncthreads();
        #pragma unroll
        for (int kk = 0; kk < 16; kk++) {
            float4 a = *(const float4*)&As[kk][ty * 4];
            float4 b = *(const float4*)&Ws[kk][tx * 4];
            acc[0][0] += a.x * b.x; acc[0][1] += a.x * b.y; acc[0][2] += a.x * b.z; acc[0][3] += a.x * b.w;
            acc[1][0] += a.y * b.x; acc[1][1] += a.y * b.y; acc[1][2] += a.y * b.z; acc[1][3] += a.y * b.w;
            acc[2][0] += a.z * b.x; acc[2][1] += a.z * b.y; acc[2][2] += a.z * b.z; acc[2][3] += a.z * b.w;
            acc[3][0] += a.w * b.x; acc[3][1] += a.w * b.y; acc[3][2] += a.w * b.z; acc[3][3] += a.w * b.w;
        }
    }
    #pragma unroll
    for (int i = 0; i < 4; i++) {
        size_t row = (size_t)(bm + ty * 4 + i);
        float4* p = (float4*)(residual + row * 256 + bn + tx * 4);
        float4 r = *p;
        r.x += acc[i][0]; r.y += acc[i][1]; r.z += acc[i][2]; r.w += acc[i][3];
        *p = r;
    }
}

// ------------------------------------------------- depthwise conv + silu
__global__ void k_conv(const float* __restrict__ xh, const float* __restrict__ cw,
                       const float* __restrict__ cb, float* __restrict__ xb) {
    int idx = blockIdx.x * 256 + threadIdx.x;      // NTOK*512
    int tok = idx >> 9, d = idx & 511;
    int b = tok >> 11, l = tok & 2047;
    const float* base = xh + (size_t)(b * 2048) * 512 + d;
    float acc = cb[d];
    for (int k = 0; k < 4; k++) {
        int t = l - 3 + k;
        if (t >= 0) acc += base[(size_t)t * 512] * cw[d * 4 + k];
    }
    xb[idx] = silu(acc);
}

// ------------------------- x_proj: block per token, LDS x row, 48 outputs
__global__ __launch_bounds__(64) void k_xproj(const float* __restrict__ xb,
                                              const float* __restrict__ xw,
                                              float* __restrict__ dbc) {
    __shared__ __align__(16) float xrow[512];
    int tok = blockIdx.x, t = threadIdx.x;
    const float* xp = xb + (size_t)tok * 512;
    #pragma unroll
    for (int i = 0; i < 8; i++) xrow[t + i * 64] = xp[t + i * 64];
    __syncthreads();
    if (t < 48) {
        const float4* w4 = (const float4*)(xw + (size_t)t * 512);
        const float4* x4 = (const float4*)xrow;
        float acc = 0.f;
        #pragma unroll 8
        for (int k4 = 0; k4 < 128; k4++) {
            float4 wv = w4[k4];
            float4 xv = x4[k4];
            acc += xv.x * wv.x + xv.y * wv.y + xv.z * wv.z + xv.w * wv.w;
        }
        dbc[(size_t)tok * 48 + t] = acc;
    }
}

// -------------------------- dt = softplus(dbc[:, :16] @ dtw^T + dtb)
__global__ void k_dt(const float* __restrict__ dbc, const float* __restrict__ dtw,
                     const float* __restrict__ dtb, float* __restrict__ dt) {
    int idx = blockIdx.x * 256 + threadIdx.x;      // NTOK*512
    int tok = idx >> 9, d = idx & 511;
    const float* row = dbc + (size_t)tok * 48;
    const float* w = dtw + d * 16;
    float acc = dtb[d];
    #pragma unroll
    for (int r = 0; r < 16; r++) acc += row[r] * w[r];
    dt[idx] = (acc > 20.f) ? acc : log1pf(expf(acc));
}

// ------------- scan phase A: per-chunk local scan from h=0 + decay product
// gid = c*16384 + bds;  bds = (b*512+d)*16+s
__global__ __launch_bounds__(256) void k_scanA(const float* __restrict__ dt,
                                               const float* __restrict__ xb,
                                               const float* __restrict__ dbc,
                                               const float* __restrict__ a_log,
                                               float* __restrict__ Aprod,
                                               float* __restrict__ Hfin) {
    int gid = blockIdx.x * 256 + threadIdx.x;      // 262144
    int bds = gid & 16383;
    int c = gid >> 14;
    int s = bds & 15;
    int d = (bds >> 4) & 511;
    int b = bds >> 13;
    float A = -expf(a_log[d * 16 + s]);
    int tok0 = b * SEQ + c * CL;
    const float* dtp = dt + (size_t)tok0 * 512 + d;
    const float* xp  = xb + (size_t)tok0 * 512 + d;
    const float* rp  = dbc + (size_t)tok0 * 48 + 16 + s;
    float h = 0.f, ap = 1.f;
    for (int t = 0; t < CL; t++) {
        float dtv = dtp[t * 512];
        float xv  = xp[t * 512];
        float Bv  = rp[t * 48];
        float dA = expf(dtv * A);
        h = dA * h + dtv * Bv * xv;
        ap *= dA;
    }
    Aprod[gid] = ap;
    Hfin[gid] = h;
}

// ------------- scan phase B: combine chunk summaries -> start states (in place)
__global__ void k_scanB(const float* __restrict__ Aprod, float* __restrict__ Hfin) {
    int bds = blockIdx.x * 256 + threadIdx.x;      // 16384
    float h = 0.f;
    for (int c = 0; c < NC; c++) {
        int i = c * 16384 + bds;
        float a = Aprod[i], f = Hfin[i];
        Hfin[i] = h;            // start state for chunk c
        h = a * h + f;
    }
}

// ------------- scan phase C: re-run chunk from start state, reduce s, gate, emit y
__global__ __launch_bounds__(256) void k_scanC(const float* __restrict__ dt,
                                               const float* __restrict__ xb,
                                               const float* __restrict__ zb,
                                               const float* __restrict__ dbc,
                                               const float* __restrict__ a_log,
                                               const float* __restrict__ Dp,
                                               const float* __restrict__ Hstart,
                                               float* __restrict__ yb) {
    int gid = blockIdx.x * 256 + threadIdx.x;      // 262144
    int bds = gid & 16383;
    int c = gid >> 14;
    int s = bds & 15;
    int d = (bds >> 4) & 511;
    int b = bds >> 13;
    float A = -expf(a_log[d * 16 + s]);
    float Dv = Dp[d];
    int tok0 = b * SEQ + c * CL;
    const float* dtp = dt + (size_t)tok0 * 512 + d;
    const float* xp  = xb + (size_t)tok0 * 512 + d;
    const float* zp  = zb + (size_t)tok0 * 512 + d;
    const float* rp  = dbc + (size_t)tok0 * 48 + 16 + s;   // B at +0, C at +16
    float* yp = yb + (size_t)tok0 * 512 + d;
    float h = Hstart[gid];
    for (int t = 0; t < CL; t++) {
        float dtv = dtp[t * 512];
        float xv  = xp[t * 512];
        float Bv  = rp[t * 48];
        float Cv  = rp[t * 48 + 16];
        float dA = expf(dtv * A);
        h = dA * h + dtv * Bv * xv;
        float contrib = h * Cv;
        contrib += __shfl_xor(contrib, 1);
        contrib += __shfl_xor(contrib, 2);
        contrib += __shfl_xor(contrib, 4);
        contrib += __shfl_xor(contrib, 8);
        if (s == 0) {
            float zv = zp[t * 512];
            yp[t * 512] = (contrib + Dv * xv) * silu(zv);
        }
    }
}

// ---------------------------------------------------------------- lm head
__global__ void k_head(const float* __restrict__ hn, const float* __restrict__ lw,
                       float* __restrict__ out) {
    int idx = blockIdx.x * 256 + threadIdx.x;      // NTOK*20 = 81920
    int tok = idx / 20, v = idx % 20;
    const float* a = hn + (size_t)tok * 256;
    const float* w = lw + (size_t)v * 256;
    float acc = 0.f;
    for (int k = 0; k < 256; k++) acc += a[k] * w[k];
    out[idx] = acc;
}

extern "C" void kernel_launch(void* const* d_in, const int* in_sizes, int n_in,
                              void* d_out, int out_size, void* d_ws, size_t ws_size,
                              hipStream_t stream) {
    const int*   ids    = (const int*)d_in[0];
    const float* emb    = (const float*)d_in[1];
    const float* in_w   = (const float*)d_in[2];
    const float* conv_w = (const float*)d_in[3];
    const float* conv_b = (const float*)d_in[4];
    const float* x_w    = (const float*)d_in[5];
    const float* dt_w   = (const float*)d_in[6];
    const float* dt_b   = (const float*)d_in[7];
    const float* a_log  = (const float*)d_in[8];
    const float* d_skip = (const float*)d_in[9];
    const float* out_w  = (const float*)d_in[10];
    const float* norm_w = (const float*)d_in[11];
    const float* norm_f = (const float*)d_in[12];
    const float* lm_w   = (const float*)d_in[13];
    float* out = (float*)d_out;

    // ---- workspace layout: 42,729,472 bytes (proven available in r5/r6) ----
    char* ws = (char*)d_ws;
    float* residual = (float*)(ws + 0);            // NTOK*256 = 4 MB
    float* hn       = (float*)(ws + 4194304);      // NTOK*256 = 4 MB  (aliased: chunk summaries)
    float* xh       = (float*)(ws + 8388608);      // NTOK*512 = 8 MB  (aliased: yb)
    float* zb       = (float*)(ws + 16777216);     // NTOK*512 = 8 MB
    float* xb       = (float*)(ws + 25165824);     // NTOK*512 = 8 MB
    float* dbc      = (float*)(ws + 33554432);     // NTOK*48  = 768 KB
    float* dt       = (float*)(ws + 34340864);     // NTOK*512 = 8 MB
    float* Aprod    = hn;                          // 262144 f32 = 1 MB (hn dead after gemm1)
    float* Hfin     = hn + 262144;                 // 262144 f32 = 1 MB
    float* yb       = xh;                          // xh dead after conv

    k_embed<<<(NTOK * 256) / 256, 256, 0, stream>>>(ids, emb, residual);

    for (int i = 0; i < N_LAYER; i++) {
        k_rmsnorm<<<NTOK, 256, 0, stream>>>(residual, norm_w + i * D_MODEL, hn);
        dim3 g1(NTOK / 64, 1024 / 64);
        k_gemm1_tiled<<<g1, 256, 0, stream>>>(hn, in_w + (size_t)i * 1024 * 256, xh, zb);
        k_conv<<<(NTOK * 512) / 256, 256, 0, stream>>>(
            xh, conv_w + (size_t)i * 512 * 4, conv_b + (size_t)i * 512, xb);
        k_xproj<<<NTOK, 64, 0, stream>>>(xb, x_w + (size_t)i * 48 * 512, dbc);
        k_dt<<<(NTOK * 512) / 256, 256, 0, stream>>>(
            dbc, dt_w + (size_t)i * 512 * 16, dt_b + (size_t)i * 512, dt);
        k_scanA<<<262144 / 256, 256, 0, stream>>>(
            dt, xb, dbc, a_log + (size_t)i * 512 * 16, Aprod, Hfin);
        k_scanB<<<16384 / 256, 256, 0, stream>>>(Aprod, Hfin);
        k_scanC<<<262144 / 256, 256, 0, stream>>>(
            dt, xb, zb, dbc, a_log + (size_t)i * 512 * 16,
            d_skip + (size_t)i * 512, Hfin, yb);
        dim3 g2(NTOK / 64, 256 / 64);
        k_gemm2_tiled<<<g2, 256, 0, stream>>>(yb, out_w + (size_t)i * 256 * 512, residual);
    }

    k_rmsnorm<<<NTOK, 256, 0, stream>>>(residual, norm_f, hn);
    k_head<<<320, 256, 0, stream>>>(hn, lm_w, out);
}

// Round 8
// 3719.269 us; speedup vs baseline: 17.8207x; 1.2448x over previous
//
#include <hip/hip_runtime.h>
#include <hip/hip_bf16.h>

#define D_MODEL 256
#define N_LAYER 16
#define VOCAB 24
#define D_INNER 512
#define D_STATE 16
#define D_CONV 4
#define DT_RANK 16
#define BATCH 2
#define SEQ 2048
#define NTOK (BATCH*SEQ)   /* 4096 */
#define EPS 1e-5f
#define NC 32              /* scan chunks */
#define CL (SEQ/NC)        /* 64 tokens per chunk */
#define NSC (BATCH*D_INNER*D_STATE)      /* 16384 scan chains */
#define NSCC (NSC*NC)                    /* 524288 chain-chunks */

__device__ __forceinline__ float silu(float v) { return v / (1.f + __expf(-v)); }

// ---------------------------------------------------------------- embedding
__global__ void k_embed(const int* __restrict__ ids, const float* __restrict__ emb,
                        float* __restrict__ residual) {
    int idx = blockIdx.x * 256 + threadIdx.x;      // NTOK*256
    int tok = idx >> 8, c = idx & 255;
    residual[idx] = emb[ids[tok] * D_MODEL + c];
}

// ---------------------------------------------------------------- rmsnorm
__global__ void k_rmsnorm(const float* __restrict__ residual, const float* __restrict__ w,
                          float* __restrict__ hn) {
    __shared__ float red[256];
    int tok = blockIdx.x, c = threadIdx.x;
    float v = residual[tok * 256 + c];
    red[c] = v * v;
    __syncthreads();
    for (int st = 128; st > 0; st >>= 1) {
        if (c < st) red[c] += red[c + st];
        __syncthreads();
    }
    float scale = rsqrtf(red[0] * (1.f / 256.f) + EPS);
    hn[tok * 256 + c] = v * scale * w[c];
}

// ---------------------- gemm1 tiled: [NTOK,256] @ [1024,256]^T -> split x/z
__global__ __launch_bounds__(256) void k_gemm1_tiled(const float* __restrict__ A,
                                                     const float* __restrict__ W,
                                                     float* __restrict__ xh,
                                                     float* __restrict__ zb) {
    __shared__ __align__(16) float As[16][64];
    __shared__ __align__(16) float Ws[16][64];
    const int bm = blockIdx.x * 64, bn = blockIdx.y * 64;
    const int tid = threadIdx.x;
    const int tx = tid & 15, ty = tid >> 4;
    const int lm = tid >> 2;         // 0..63
    const int lk = (tid & 3) * 4;    // 0,4,8,12
    float acc[4][4] = {};
    for (int k0 = 0; k0 < 256; k0 += 16) {
        float4 av = *(const float4*)(A + (size_t)(bm + lm) * 256 + k0 + lk);
        float4 wv = *(const float4*)(W + (size_t)(bn + lm) * 256 + k0 + lk);
        __syncthreads();
        As[lk + 0][lm] = av.x; As[lk + 1][lm] = av.y;
        As[lk + 2][lm] = av.z; As[lk + 3][lm] = av.w;
        Ws[lk + 0][lm] = wv.x; Ws[lk + 1][lm] = wv.y;
        Ws[lk + 2][lm] = wv.z; Ws[lk + 3][lm] = wv.w;
        __syncthreads();
        #pragma unroll
        for (int kk = 0; kk < 16; kk++) {
            float4 a = *(const float4*)&As[kk][ty * 4];
            float4 b = *(const float4*)&Ws[kk][tx * 4];
            acc[0][0] += a.x * b.x; acc[0][1] += a.x * b.y; acc[0][2] += a.x * b.z; acc[0][3] += a.x * b.w;
            acc[1][0] += a.y * b.x; acc[1][1] += a.y * b.y; acc[1][2] += a.y * b.z; acc[1][3] += a.y * b.w;
            acc[2][0] += a.z * b.x; acc[2][1] += a.z * b.y; acc[2][2] += a.z * b.z; acc[2][3] += a.z * b.w;
            acc[3][0] += a.w * b.x; acc[3][1] += a.w * b.y; acc[3][2] += a.w * b.z; acc[3][3] += a.w * b.w;
        }
    }
    #pragma unroll
    for (int i = 0; i < 4; i++) {
        size_t row = (size_t)(bm + ty * 4 + i);
        float4 v = make_float4(acc[i][0], acc[i][1], acc[i][2], acc[i][3]);
        if (bn < 512) *(float4*)(xh + row * 512 + bn + tx * 4) = v;          // uniform per block
        else          *(float4*)(zb + row * 512 + (bn - 512) + tx * 4) = v;
    }
}

// ------------------- gemm2 tiled: residual += [NTOK,512] @ [256,512]^T
__global__ __launch_bounds__(256) void k_gemm2_tiled(const float* __restrict__ A,
                                                     const float* __restrict__ W,
                                                     float* __restrict__ residual) {
    __shared__ __align__(16) float As[16][64];
    __shared__ __align__(16) float Ws[16][64];
    const int bm = blockIdx.x * 64, bn = blockIdx.y * 64;
    const int tid = threadIdx.x;
    const int tx = tid & 15, ty = tid >> 4;
    const int lm = tid >> 2;
    const int lk = (tid & 3) * 4;
    float acc[4][4] = {};
    for (int k0 = 0; k0 < 512; k0 += 16) {
        float4 av = *(const float4*)(A + (size_t)(bm + lm) * 512 + k0 + lk);
        float4 wv = *(const float4*)(W + (size_t)(bn + lm) * 512 + k0 + lk);
        __syncthreads();
        As[lk + 0][lm] = av.x; As[lk + 1][lm] = av.y;
        As[lk + 2][lm] = av.z; As[lk + 3][lm] = av.w;
        Ws[lk + 0][lm] = wv.x; Ws[lk + 1][lm] = wv.y;
        Ws[lk + 2][lm] = wv.z; Ws[lk + 3][lm] = wv.w;
        __syncthreads();
        #pragma unroll
        for (int kk = 0; kk < 16; kk++) {
            float4 a = *(const float4*)&As[kk][ty * 4];
            float4 b = *(const float4*)&Ws[kk][tx * 4];
            acc[0][0] += a.x * b.x; acc[0][1] += a.x * b.y; acc[0][2] += a.x * b.z; acc[0][3] += a.x * b.w;
            acc[1][0] += a.y * b.x; acc[1][1] += a.y * b.y; acc[1][2] += a.y * b.z; acc[1][3] += a.y * b.w;
            acc[2][0] += a.z * b.x; acc[2][1] += a.z * b.y; acc[2][2] += a.z * b.z; acc[2][3] += a.z * b.w;
            acc[3][0] += a.w * b.x; acc[3][1] += a.w * b.y; acc[3][2] += a.w * b.z; acc[3][3] += a.w * b.w;
        }
    }
    #pragma unroll
    for (int i = 0; i < 4; i++) {
        size_t row = (size_t)(bm + ty * 4 + i);
        float4* p = (float4*)(residual + row * 256 + bn + tx * 4);
        float4 r = *p;
        r.x += acc[i][0]; r.y += acc[i][1]; r.z += acc[i][2]; r.w += acc[i][3];
        *p = r;
    }
}

// ------------------------------------------------- depthwise conv + silu
__global__ void k_conv(const float* __restrict__ xh, const float* __restrict__ cw,
                       const float* __restrict__ cb, float* __restrict__ xb) {
    int idx = blockIdx.x * 256 + threadIdx.x;      // NTOK*512
    int tok = idx >> 9, d = idx & 511;
    int b = tok >> 11, l = tok & 2047;
    const float* base = xh + (size_t)(b * 2048) * 512 + d;
    float acc = cb[d];
    #pragma unroll
    for (int k = 0; k < 4; k++) {
        int t = l - 3 + k;
        if (t >= 0) acc += base[(size_t)t * 512] * cw[d * 4 + k];
    }
    xb[idx] = silu(acc);
}

// ------------------------- x_proj: block per token, LDS x row, 48 outputs
__global__ __launch_bounds__(64) void k_xproj(const float* __restrict__ xb,
                                              const float* __restrict__ xw,
                                              float* __restrict__ dbc) {
    __shared__ __align__(16) float xrow[512];
    int tok = blockIdx.x, t = threadIdx.x;
    const float* xp = xb + (size_t)tok * 512;
    #pragma unroll
    for (int i = 0; i < 8; i++) xrow[t + i * 64] = xp[t + i * 64];
    __syncthreads();
    if (t < 48) {
        const float4* w4 = (const float4*)(xw + (size_t)t * 512);
        const float4* x4 = (const float4*)xrow;
        float acc = 0.f;
        #pragma unroll 8
        for (int k4 = 0; k4 < 128; k4++) {
            float4 wv = w4[k4];
            float4 xv = x4[k4];
            acc += xv.x * wv.x + xv.y * wv.y + xv.z * wv.z + xv.w * wv.w;
        }
        dbc[(size_t)tok * 48 + t] = acc;
    }
}

// -------------------------- dt = softplus(dbc[:, :16] @ dtw^T + dtb)
__global__ void k_dt(const float* __restrict__ dbc, const float* __restrict__ dtw,
                     const float* __restrict__ dtb, float* __restrict__ dt) {
    int idx = blockIdx.x * 256 + threadIdx.x;      // NTOK*512
    int tok = idx >> 9, d = idx & 511;
    const float* row = dbc + (size_t)tok * 48;
    const float* w = dtw + d * 16;
    float acc = dtb[d];
    #pragma unroll
    for (int r = 0; r < 16; r++) acc += row[r] * w[r];
    dt[idx] = (acc > 20.f) ? acc : __logf(1.f + __expf(acc));
}

// ------------- scan phase A: per-chunk local scan from h=0 + decay product
// gid = c*NSC + bds;  bds = (b*512+d)*16+s
__global__ __launch_bounds__(256) void k_scanA(const float* __restrict__ dt,
                                               const float* __restrict__ xb,
                                               const float* __restrict__ dbc,
                                               const float* __restrict__ a_log,
                                               float* __restrict__ Aprod,
                                               float* __restrict__ Hfin) {
    int gid = blockIdx.x * 256 + threadIdx.x;      // NSCC
    int bds = gid & (NSC - 1);
    int c = gid >> 14;
    int s = bds & 15;
    int d = (bds >> 4) & 511;
    int b = bds >> 13;
    float A = -__expf(a_log[d * 16 + s]);
    int tok0 = b * SEQ + c * CL;
    const float* dtp = dt + (size_t)tok0 * 512 + d;
    const float* xp  = xb + (size_t)tok0 * 512 + d;
    const float* rp  = dbc + (size_t)tok0 * 48 + 16 + s;
    float h = 0.f, ap = 1.f;
    #pragma unroll 4
    for (int t = 0; t < CL; t++) {
        float dtv = dtp[t * 512];
        float xv  = xp[t * 512];
        float Bv  = rp[t * 48];
        float dA = __expf(dtv * A);
        h = dA * h + dtv * Bv * xv;
        ap *= dA;
    }
    Aprod[gid] = ap;
    Hfin[gid] = h;
}

// ------------- scan phase B: combine chunk summaries -> start states (in place)
__global__ void k_scanB(const float* __restrict__ Aprod, float* __restrict__ Hfin) {
    int bds = blockIdx.x * 256 + threadIdx.x;      // NSC
    float h = 0.f;
    for (int c = 0; c < NC; c++) {
        int i = c * NSC + bds;
        float a = Aprod[i], f = Hfin[i];
        Hfin[i] = h;            // start state for chunk c
        h = a * h + f;
    }
}

// ------------- scan phase C: re-run chunk from start state, reduce s, gate, emit y
__global__ __launch_bounds__(256) void k_scanC(const float* __restrict__ dt,
                                               const float* __restrict__ xb,
                                               const float* __restrict__ zb,
                                               const float* __restrict__ dbc,
                                               const float* __restrict__ a_log,
                                               const float* __restrict__ Dp,
                                               const float* __restrict__ Hstart,
                                               float* __restrict__ yb) {
    int gid = blockIdx.x * 256 + threadIdx.x;      // NSCC
    int bds = gid & (NSC - 1);
    int c = gid >> 14;
    int s = bds & 15;
    int d = (bds >> 4) & 511;
    int b = bds >> 13;
    float A = -__expf(a_log[d * 16 + s]);
    float Dv = Dp[d];
    int tok0 = b * SEQ + c * CL;
    const float* dtp = dt + (size_t)tok0 * 512 + d;
    const float* xp  = xb + (size_t)tok0 * 512 + d;
    const float* zp  = zb + (size_t)tok0 * 512 + d;
    const float* rp  = dbc + (size_t)tok0 * 48 + 16 + s;   // B at +0, C at +16
    float* yp = yb + (size_t)tok0 * 512 + d;
    float h = Hstart[gid];
    #pragma unroll 2
    for (int t = 0; t < CL; t++) {
        float dtv = dtp[t * 512];
        float xv  = xp[t * 512];
        float Bv  = rp[t * 48];
        float Cv  = rp[t * 48 + 16];
        float dA = __expf(dtv * A);
        h = dA * h + dtv * Bv * xv;
        float contrib = h * Cv;
        contrib += __shfl_xor(contrib, 1);
        contrib += __shfl_xor(contrib, 2);
        contrib += __shfl_xor(contrib, 4);
        contrib += __shfl_xor(contrib, 8);
        if (s == 0) {
            float zv = zp[t * 512];
            yp[t * 512] = (contrib + Dv * xv) * silu(zv);
        }
    }
}

// ---------------------------------------------------------------- lm head
__global__ void k_head(const float* __restrict__ hn, const float* __restrict__ lw,
                       float* __restrict__ out) {
    int idx = blockIdx.x * 256 + threadIdx.x;      // NTOK*20 = 81920
    int tok = idx / 20, v = idx % 20;
    const float* a = hn + (size_t)tok * 256;
    const float* w = lw + (size_t)v * 256;
    float acc = 0.f;
    for (int k = 0; k < 256; k++) acc += a[k] * w[k];
    out[idx] = acc;
}

extern "C" void kernel_launch(void* const* d_in, const int* in_sizes, int n_in,
                              void* d_out, int out_size, void* d_ws, size_t ws_size,
                              hipStream_t stream) {
    const int*   ids    = (const int*)d_in[0];
    const float* emb    = (const float*)d_in[1];
    const float* in_w   = (const float*)d_in[2];
    const float* conv_w = (const float*)d_in[3];
    const float* conv_b = (const float*)d_in[4];
    const float* x_w    = (const float*)d_in[5];
    const float* dt_w   = (const float*)d_in[6];
    const float* dt_b   = (const float*)d_in[7];
    const float* a_log  = (const float*)d_in[8];
    const float* d_skip = (const float*)d_in[9];
    const float* out_w  = (const float*)d_in[10];
    const float* norm_w = (const float*)d_in[11];
    const float* norm_f = (const float*)d_in[12];
    const float* lm_w   = (const float*)d_in[13];
    float* out = (float*)d_out;

    // ---- workspace layout: 42,729,472 bytes (proven available in r5/r6) ----
    char* ws = (char*)d_ws;
    float* residual = (float*)(ws + 0);            // NTOK*256 = 4 MB
    float* hn       = (float*)(ws + 4194304);      // NTOK*256 = 4 MB  (aliased: chunk summaries)
    float* xh       = (float*)(ws + 8388608);      // NTOK*512 = 8 MB  (aliased: yb)
    float* zb       = (float*)(ws + 16777216);     // NTOK*512 = 8 MB
    float* xb       = (float*)(ws + 25165824);     // NTOK*512 = 8 MB
    float* dbc      = (float*)(ws + 33554432);     // NTOK*48  = 768 KB
    float* dt       = (float*)(ws + 34340864);     // NTOK*512 = 8 MB
    float* Aprod    = hn;                          // NSCC f32 = 2 MB (hn dead after gemm1)
    float* Hfin     = hn + NSCC;                   // NSCC f32 = 2 MB
    float* yb       = xh;                          // xh dead after conv

    k_embed<<<(NTOK * 256) / 256, 256, 0, stream>>>(ids, emb, residual);

    for (int i = 0; i < N_LAYER; i++) {
        k_rmsnorm<<<NTOK, 256, 0, stream>>>(residual, norm_w + i * D_MODEL, hn);
        dim3 g1(NTOK / 64, 1024 / 64);
        k_gemm1_tiled<<<g1, 256, 0, stream>>>(hn, in_w + (size_t)i * 1024 * 256, xh, zb);
        k_conv<<<(NTOK * 512) / 256, 256, 0, stream>>>(
            xh, conv_w + (size_t)i * 512 * 4, conv_b + (size_t)i * 512, xb);
        k_xproj<<<NTOK, 64, 0, stream>>>(xb, x_w + (size_t)i * 48 * 512, dbc);
        k_dt<<<(NTOK * 512) / 256, 256, 0, stream>>>(
            dbc, dt_w + (size_t)i * 512 * 16, dt_b + (size_t)i * 512, dt);
        k_scanA<<<NSCC / 256, 256, 0, stream>>>(
            dt, xb, dbc, a_log + (size_t)i * 512 * 16, Aprod, Hfin);
        k_scanB<<<NSC / 256, 256, 0, stream>>>(Aprod, Hfin);
        k_scanC<<<NSCC / 256, 256, 0, stream>>>(
            dt, xb, zb, dbc, a_log + (size_t)i * 512 * 16,
            d_skip + (size_t)i * 512, Hfin, yb);
        dim3 g2(NTOK / 64, 256 / 64);
        k_gemm2_tiled<<<g2, 256, 0, stream>>>(yb, out_w + (size_t)i * 256 * 512, residual);
    }

    k_rmsnorm<<<NTOK, 256, 0, stream>>>(residual, norm_f, hn);
    k_head<<<320, 256, 0, stream>>>(hn, lm_w, out);
}